// Round 1
// 2062.956 us; speedup vs baseline: 1.5380x; 1.5380x over previous
//
#include <hip/hip_runtime.h>
#include <stdint.h>

// Problem constants
#define BB   64
#define TT   512
#define HT   256
#define OO   128
#define GATES 1024   // 4*H

// lstm weight layout (R8/R9): 512 threads, thread (s=tid>>8, q=tid&255) owns
// gate rows 4q..4q+3 and k in [128s, 128s+128).  Unit = 4 consecutive k;
// processed in PAIRS (8 k) sharing one b128 h broadcast.
//
// R10: previous split (6/4/6) declared 96 VGPRs of weights resident but the
// allocator demoted them (VGPR_Count=88 < 96) -> weights were re-read from
// L2/scratch every step (~384KB/step through L1 ~= the whole 6192cy step).
// Fix: amdgpu_waves_per_eu(2,2) (LDS already limits to 1 WG/CU = 2 waves/EU,
// so the honest VGPR budget is 256) and rebalance to 10 reg / 4 LDS / 2 stream.
#define PREG 10                    // pairs in VGPRs: 20 units = 160 VGPR/lane
#define PLDS 4                     // pairs in LDS: 8 units = 128 KB
#define PSTR 2                     // pairs streamed from L2/step: 64 KB
#define UREG (2*PREG)
#define ULDS (2*PLDS)

typedef _Float16 half_t;
typedef _Float16 half2_t __attribute__((ext_vector_type(2)));
typedef _Float16 f16x8  __attribute__((ext_vector_type(8)));
typedef float    f32x4  __attribute__((ext_vector_type(4)));

__device__ __forceinline__ half2_t h2_(unsigned int x) {
    return __builtin_bit_cast(half2_t, x);
}
// lgkm-only workgroup barrier (R9 win): no vmcnt drain per step.
#define WG_BARRIER() do { __builtin_amdgcn_s_waitcnt(0xC07F); \
                          __builtin_amdgcn_s_barrier(); } while (0)

__device__ __forceinline__ float fast_sig(float x) {
    return __builtin_amdgcn_rcpf(1.0f + __expf(-x));
}
__device__ __forceinline__ float fast_tanh(float x) {
    float t = __expf(2.0f * x);
    return 1.0f - 2.0f * __builtin_amdgcn_rcpf(t + 1.0f);
}

// ---------------------------------------------------------------------------
// Embedding gather + decoder_action output
__global__ __launch_bounds__(256) void embed_kernel(
    const int* __restrict__ actions, const float* __restrict__ emb_table,
    float* __restrict__ X, float* __restrict__ dact)
{
    int row = blockIdx.x;
    int t = row & (TT - 1);
    int id = (t == 0) ? 0 : actions[row - 1];
    X[(int64_t)row * HT + threadIdx.x] = emb_table[(int64_t)id * HT + threadIdx.x];
    if (threadIdx.x == 0) dact[row] = (float)actions[row];
}

// ---------------------------------------------------------------------------
// Repack Whh to fp16 (R8 layout, unit-indexed).
__global__ __launch_bounds__(256) void repack_whh_h_kernel(
    const float* __restrict__ Whh, uint4* __restrict__ Wpkh)
{
    int idx = blockIdx.x * 256 + threadIdx.x;   // 0..65535
    int tid = idx & 511;
    int ab  = (idx >> 9) & 1;
    int u   = (idx >> 10) & 31;
    int l   = idx >> 15;
    int s = tid >> 8, q = tid & 255;
    int r0 = 4 * q + 2 * ab;
    int k  = 128 * s + 4 * u;
    const float* base = Whh + (int64_t)l * (GATES * HT);
    const float4 a = *(const float4*)(base + (int64_t)r0 * HT + k);
    const float4 b = *(const float4*)(base + (int64_t)(r0 + 1) * HT + k);
    half2_t p0 = {(half_t)a.x, (half_t)a.y};
    half2_t p1 = {(half_t)a.z, (half_t)a.w};
    half2_t p2 = {(half_t)b.x, (half_t)b.y};
    half2_t p3 = {(half_t)b.z, (half_t)b.w};
    uint4 o;
    o.x = __builtin_bit_cast(unsigned int, p0);
    o.y = __builtin_bit_cast(unsigned int, p1);
    o.z = __builtin_bit_cast(unsigned int, p2);
    o.w = __builtin_bit_cast(unsigned int, p3);
    Wpkh[idx] = o;
}

// ---------------------------------------------------------------------------
// MFMA fp16 GEMM: C = act( A @ op(B) + bias1 + bias2 ), fp32 in/out.
// TRANS_B: B is [N,K] ldb (dot along k). else B is [K,N] ldb.
// BM=BN=128, BK=32; 256 threads = 4 waves, each owns a 64x64 quadrant
// (4x4 mfma_f32_16x16x32_f16 tiles).  fp32->fp16 conversion in staging.
// LDS rows padded to 40 halfs: fragment b128 reads land 2-way max (free).
// Layouts (verified, cdna_hip_programming §3): A/B frag [m|n]=lane&15,
// k=quad*8+j; C/D col=lane&15, row=quad*4+reg.
template<bool TRANS_B, int ACT>
__global__ __launch_bounds__(256) void mfma_gemm_kernel(
    const float* __restrict__ A, const float* __restrict__ Bm,
    float* __restrict__ C,
    int K, int lda, int ldb, int ldc,
    int64_t sA, int64_t sB, int64_t sC,
    const float* __restrict__ bias1, const float* __restrict__ bias2)
{
    constexpr int BM = 128, BN = 128, BK = 32;
    constexpr int LDT = BK + 8;                  // 40 halfs = 80 B row stride
    __shared__ __align__(16) half_t Asl[BM * LDT];   // 10 KB
    __shared__ __align__(16) half_t Bsl[BN * LDT];   // 10 KB

    const int tid  = threadIdx.x;
    const int wave = tid >> 6;
    const int lane = tid & 63;
    const int wm = (wave & 1) * 64;
    const int wn = (wave >> 1) * 64;
    const int m0 = blockIdx.y * BM;
    const int n0 = blockIdx.x * BN;
    A  += (int64_t)blockIdx.z * sA;
    Bm += (int64_t)blockIdx.z * sB;
    C  += (int64_t)blockIdx.z * sC;

    const int fm = lane & 15;
    const int qd = lane >> 4;

    f32x4 acc[4][4] = {};

    for (int k0 = 0; k0 < K; k0 += BK) {
        // --- stage A (128 x 32 fp32 -> fp16), coalesced 128B per 8 lanes
        #pragma unroll
        for (int i = 0; i < 4; i++) {
            int idx = tid + i * 256;             // 0..1023
            int r  = idx >> 3;                   // 0..127
            int kq = idx & 7;                    // 0..7
            float4 v = *(const float4*)(A + (int64_t)(m0 + r) * lda + k0 + kq * 4);
            half_t* d = &Asl[r * LDT + kq * 4];
            d[0] = (half_t)v.x; d[1] = (half_t)v.y;
            d[2] = (half_t)v.z; d[3] = (half_t)v.w;
        }
        // --- stage B
        if (TRANS_B) {
            #pragma unroll
            for (int i = 0; i < 4; i++) {
                int idx = tid + i * 256;
                int r  = idx >> 3;
                int kq = idx & 7;
                float4 v = *(const float4*)(Bm + (int64_t)(n0 + r) * ldb + k0 + kq * 4);
                half_t* d = &Bsl[r * LDT + kq * 4];
                d[0] = (half_t)v.x; d[1] = (half_t)v.y;
                d[2] = (half_t)v.z; d[3] = (half_t)v.w;
            }
        } else {
            // B[K][N]: read rows of k (coalesced along n), write transposed
            #pragma unroll
            for (int i = 0; i < 4; i++) {
                int idx = tid + i * 256;
                int kk = idx >> 5;               // 0..31
                int nq = idx & 31;               // 0..31 (x4 n)
                float4 v = *(const float4*)(Bm + (int64_t)(k0 + kk) * ldb + n0 + nq * 4);
                Bsl[(nq * 4 + 0) * LDT + kk] = (half_t)v.x;
                Bsl[(nq * 4 + 1) * LDT + kk] = (half_t)v.y;
                Bsl[(nq * 4 + 2) * LDT + kk] = (half_t)v.z;
                Bsl[(nq * 4 + 3) * LDT + kk] = (half_t)v.w;
            }
        }
        __syncthreads();

        f16x8 af[4], bf[4];
        #pragma unroll
        for (int t = 0; t < 4; t++)
            af[t] = *(const f16x8*)&Asl[(wm + t * 16 + fm) * LDT + qd * 8];
        #pragma unroll
        for (int t = 0; t < 4; t++)
            bf[t] = *(const f16x8*)&Bsl[(wn + t * 16 + fm) * LDT + qd * 8];
        #pragma unroll
        for (int mt = 0; mt < 4; mt++)
            #pragma unroll
            for (int nt = 0; nt < 4; nt++)
                acc[mt][nt] = __builtin_amdgcn_mfma_f32_16x16x32_f16(
                                  af[mt], bf[nt], acc[mt][nt], 0, 0, 0);
        __syncthreads();
    }

    // --- epilogue: D col=lane&15, row=qd*4+reg
    #pragma unroll
    for (int nt = 0; nt < 4; nt++) {
        int n = n0 + wn + nt * 16 + fm;
        float bv = 0.0f;
        if (bias1) bv += bias1[n];
        if (bias2) bv += bias2[n];
        #pragma unroll
        for (int mt = 0; mt < 4; mt++) {
            #pragma unroll
            for (int r = 0; r < 4; r++) {
                int m = m0 + wm + mt * 16 + qd * 4 + r;
                float v = acc[mt][nt][r] + bv;
                if (ACT == 1) v = tanhf(v);
                C[(int64_t)m * ldc + n] = v;
            }
        }
    }
}

// ---------------------------------------------------------------------------
// Generic fp32 tiled GEMM (kept for attention + output chain precision).
template<bool TRANS_B, int ACT>
__global__ __launch_bounds__(256) void gemm128_kernel(
    const float* __restrict__ A, const float* __restrict__ Bm,
    float* __restrict__ C,
    int K, int lda, int ldb, int ldc,
    int64_t sA, int64_t sB, int64_t sC,
    const float* __restrict__ bias1, const float* __restrict__ bias2)
{
    constexpr int BM = 128, BN = 128, BK = 16;
    __shared__ __align__(16) float As[BK][BM + 4];
    __shared__ __align__(16) float Bs[BK][BN + 4];

    const int tid = threadIdx.x;
    const int m0 = blockIdx.y * BM;
    const int n0 = blockIdx.x * BN;
    A  += (int64_t)blockIdx.z * sA;
    Bm += (int64_t)blockIdx.z * sB;
    C  += (int64_t)blockIdx.z * sC;

    const int tm = tid & 15;
    const int tn = tid >> 4;

    float acc[8][8] = {};

    for (int k0 = 0; k0 < K; k0 += BK) {
        #pragma unroll
        for (int i = 0; i < 2; i++) {
            int idx = tid + i * 256;
            int ar = idx >> 2;
            int ak = (idx & 3) * 4;
            const float4 v = *(const float4*)(A + (int64_t)(m0 + ar) * lda + k0 + ak);
            As[ak + 0][ar] = v.x; As[ak + 1][ar] = v.y;
            As[ak + 2][ar] = v.z; As[ak + 3][ar] = v.w;
        }
        if (TRANS_B) {
            #pragma unroll
            for (int i = 0; i < 2; i++) {
                int idx = tid + i * 256;
                int br = idx >> 2;
                int bk = (idx & 3) * 4;
                const float4 v = *(const float4*)(Bm + (int64_t)(n0 + br) * ldb + k0 + bk);
                Bs[bk + 0][br] = v.x; Bs[bk + 1][br] = v.y;
                Bs[bk + 2][br] = v.z; Bs[bk + 3][br] = v.w;
            }
        } else {
            #pragma unroll
            for (int i = 0; i < 2; i++) {
                int idx = tid + i * 256;
                int bk = idx >> 5;
                int bn = (idx & 31) * 4;
                const float4 v = *(const float4*)(Bm + (int64_t)(k0 + bk) * ldb + n0 + bn);
                *(float4*)&Bs[bk][bn] = v;
            }
        }
        __syncthreads();

        #pragma unroll
        for (int k = 0; k < BK; k++) {
            float a[8], b[8];
            *(float4*)&a[0] = *(const float4*)&As[k][tm * 8];
            *(float4*)&a[4] = *(const float4*)&As[k][tm * 8 + 4];
            *(float4*)&b[0] = *(const float4*)&Bs[k][tn * 8];
            *(float4*)&b[4] = *(const float4*)&Bs[k][tn * 8 + 4];
            #pragma unroll
            for (int i = 0; i < 8; i++)
                #pragma unroll
                for (int j = 0; j < 8; j++)
                    acc[i][j] += a[i] * b[j];
        }
        __syncthreads();
    }

    float bv[8];
    #pragma unroll
    for (int j = 0; j < 8; j++) {
        int n = n0 + tn * 8 + j;
        float b = 0.0f;
        if (bias1) b += bias1[n];
        if (bias2) b += bias2[n];
        bv[j] = b;
    }
    #pragma unroll
    for (int i = 0; i < 8; i++) {
        int64_t m = m0 + tm * 8 + i;
        float o[8];
        #pragma unroll
        for (int j = 0; j < 8; j++) {
            float v = acc[i][j] + bv[j];
            if (ACT == 1) v = tanhf(v);
            o[j] = v;
        }
        *(float4*)(C + m * ldc + n0 + tn * 8)     = make_float4(o[0], o[1], o[2], o[3]);
        *(float4*)(C + m * ldc + n0 + tn * 8 + 4) = make_float4(o[4], o[5], o[6], o[7]);
    }
}

// ---------------------------------------------------------------------------
#define PAIR_DOT(wa0, wb0, wa1, wb1, h4)                                  \
    do {                                                                   \
        a0 = __builtin_amdgcn_fdot2(h2_((wa0).x), h2_((h4).x), a0, false); \
        a0 = __builtin_amdgcn_fdot2(h2_((wa0).y), h2_((h4).y), a0, false); \
        a1 = __builtin_amdgcn_fdot2(h2_((wa0).z), h2_((h4).x), a1, false); \
        a1 = __builtin_amdgcn_fdot2(h2_((wa0).w), h2_((h4).y), a1, false); \
        a2 = __builtin_amdgcn_fdot2(h2_((wb0).x), h2_((h4).x), a2, false); \
        a2 = __builtin_amdgcn_fdot2(h2_((wb0).y), h2_((h4).y), a2, false); \
        a3 = __builtin_amdgcn_fdot2(h2_((wb0).z), h2_((h4).x), a3, false); \
        a3 = __builtin_amdgcn_fdot2(h2_((wb0).w), h2_((h4).y), a3, false); \
        a0 = __builtin_amdgcn_fdot2(h2_((wa1).x), h2_((h4).z), a0, false); \
        a0 = __builtin_amdgcn_fdot2(h2_((wa1).y), h2_((h4).w), a0, false); \
        a1 = __builtin_amdgcn_fdot2(h2_((wa1).z), h2_((h4).z), a1, false); \
        a1 = __builtin_amdgcn_fdot2(h2_((wa1).w), h2_((h4).w), a1, false); \
        a2 = __builtin_amdgcn_fdot2(h2_((wb1).x), h2_((h4).z), a2, false); \
        a2 = __builtin_amdgcn_fdot2(h2_((wb1).y), h2_((h4).w), a2, false); \
        a3 = __builtin_amdgcn_fdot2(h2_((wb1).z), h2_((h4).z), a3, false); \
        a3 = __builtin_amdgcn_fdot2(h2_((wb1).w), h2_((h4).w), a3, false); \
    } while (0)

// LSTM recurrence (R10): weight-persistent, fp16 fdot2, 4-rows/thread k-split,
// pair-wise b128 h broadcasts, lgkm-only barriers.
// amdgpu_waves_per_eu(2,2): LDS (136.5KB) limits to 1 WG/CU = 2 waves/EU
// anyway; declaring it unlocks the full 256-VGPR budget so the 160 VGPRs of
// resident weights survive register allocation (R9's silently didn't: VGPR=88).
__global__ __launch_bounds__(512)
__attribute__((amdgpu_waves_per_eu(2, 2)))
void lstm_rec_kernel(
    const float* __restrict__ Ag,
    const uint4* __restrict__ Wpk,
    const float* __restrict__ h0l,
    const float* __restrict__ c0l,
    float* __restrict__ X, int ldx)
{
    const int b = blockIdx.x;
    const int tid = threadIdx.x;
    const int s = tid >> 8;
    const int q = tid & 255;

    __shared__ __align__(16) uint4  Wlh[ULDS * 2 * 512];   // 128 KB
    __shared__ __align__(16) float  gsh2[2 * GATES];       // 8 KB
    __shared__ __align__(16) half_t hsh_h[HT];             // 512 B

    uint4 wreg[2 * UREG];
    #pragma unroll
    for (int u = 0; u < UREG; u++) {
        wreg[2 * u]     = Wpk[(u * 2 + 0) * 512 + tid];
        wreg[2 * u + 1] = Wpk[(u * 2 + 1) * 512 + tid];
    }
    #pragma unroll
    for (int v = 0; v < ULDS; v++) {
        Wlh[(v * 2 + 0) * 512 + tid] = Wpk[((UREG + v) * 2 + 0) * 512 + tid];
        Wlh[(v * 2 + 1) * 512 + tid] = Wpk[((UREG + v) * 2 + 1) * 512 + tid];
    }
    const uint4* __restrict__ Ws = Wpk + (UREG + ULDS) * 2 * 512;

    if (tid < HT) hsh_h[tid] = (half_t)h0l[b * HT + tid];
    float c = (tid < HT) ? c0l[b * HT + tid] : 0.0f;
    __syncthreads();

    const uint4* hp4 = (const uint4*)hsh_h;
    const int hb = 16 * s;
    const float* AgB = Ag + (int64_t)b * TT * GATES;

    for (int st = 0; st < TT; st++) {
        float4 aval = make_float4(0.f, 0.f, 0.f, 0.f);
        if (s == 0) aval = *(const float4*)(AgB + (int64_t)st * GATES + 4 * q);

        float a0 = 0.f, a1 = 0.f, a2 = 0.f, a3 = 0.f;

        #pragma unroll 2
        for (int p = 0; p < PSTR; p++) {
            uint4 wa0 = Ws[(p * 4 + 0) * 512 + tid];
            uint4 wb0 = Ws[(p * 4 + 1) * 512 + tid];
            uint4 wa1 = Ws[(p * 4 + 2) * 512 + tid];
            uint4 wb1 = Ws[(p * 4 + 3) * 512 + tid];
            uint4 h4  = hp4[hb + PREG + PLDS + p];
            PAIR_DOT(wa0, wb0, wa1, wb1, h4);
        }
        #pragma unroll
        for (int p = 0; p < PLDS; p++) {
            uint4 wa0 = Wlh[(p * 4 + 0) * 512 + tid];
            uint4 wb0 = Wlh[(p * 4 + 1) * 512 + tid];
            uint4 wa1 = Wlh[(p * 4 + 2) * 512 + tid];
            uint4 wb1 = Wlh[(p * 4 + 3) * 512 + tid];
            uint4 h4  = hp4[hb + PREG + p];
            PAIR_DOT(wa0, wb0, wa1, wb1, h4);
        }
        #pragma unroll
        for (int p = 0; p < PREG; p++) {
            uint4 h4 = hp4[hb + p];
            PAIR_DOT(wreg[4 * p], wreg[4 * p + 1], wreg[4 * p + 2], wreg[4 * p + 3], h4);
        }

        a0 += aval.x; a1 += aval.y; a2 += aval.z; a3 += aval.w;
        *(float4*)&gsh2[s * GATES + 4 * q] = make_float4(a0, a1, a2, a3);
        WG_BARRIER();

        if (tid < HT) {
            float gi = gsh2[tid]          + gsh2[GATES + tid];
            float gf = gsh2[HT + tid]     + gsh2[GATES + HT + tid];
            float gg = gsh2[2 * HT + tid] + gsh2[GATES + 2 * HT + tid];
            float go = gsh2[3 * HT + tid] + gsh2[GATES + 3 * HT + tid];
            c = fast_sig(gf) * c + fast_sig(gi) * fast_tanh(gg);
            float h = fast_sig(go) * fast_tanh(c);
            X[((int64_t)b * TT + st) * ldx + tid] = h;
            hsh_h[tid] = (half_t)h;
        }
        WG_BARRIER();
    }
}

// ---------------------------------------------------------------------------
__global__ __launch_bounds__(256) void softmax512_kernel(float* __restrict__ S)
{
    int row = blockIdx.x * 4 + (threadIdx.x >> 6);
    int lane = threadIdx.x & 63;
    float* p = S + (int64_t)row * 512 + lane * 8;
    float4 v0 = *(float4*)p;
    float4 v1 = *(float4*)(p + 4);
    float m = fmaxf(fmaxf(fmaxf(v0.x, v0.y), fmaxf(v0.z, v0.w)),
                    fmaxf(fmaxf(v1.x, v1.y), fmaxf(v1.z, v1.w)));
    #pragma unroll
    for (int off = 32; off; off >>= 1) m = fmaxf(m, __shfl_xor(m, off));
    v0.x = __expf(v0.x - m); v0.y = __expf(v0.y - m);
    v0.z = __expf(v0.z - m); v0.w = __expf(v0.w - m);
    v1.x = __expf(v1.x - m); v1.y = __expf(v1.y - m);
    v1.z = __expf(v1.z - m); v1.w = __expf(v1.w - m);
    float s = v0.x + v0.y + v0.z + v0.w + v1.x + v1.y + v1.z + v1.w;
    #pragma unroll
    for (int off = 32; off; off >>= 1) s += __shfl_xor(s, off);
    float inv = 1.0f / s;
    v0.x *= inv; v0.y *= inv; v0.z *= inv; v0.w *= inv;
    v1.x *= inv; v1.y *= inv; v1.z *= inv; v1.w *= inv;
    *(float4*)p = v0;
    *(float4*)(p + 4) = v1;
}

__global__ __launch_bounds__(256) void values_kernel(
    const float* __restrict__ Q, const float* __restrict__ L, float* __restrict__ V)
{
    int row = blockIdx.x * 4 + (threadIdx.x >> 6);
    int lane = threadIdx.x & 63;
    float2 q = *(const float2*)(Q + (int64_t)row * OO + lane * 2);
    float2 l = *(const float2*)(L + (int64_t)row * OO + lane * 2);
    float s = q.x * l.x + q.y * l.y;
    #pragma unroll
    for (int off = 32; off; off >>= 1) s += __shfl_xor(s, off);
    if (lane == 0) V[row] = s;
}

// ---------------------------------------------------------------------------
extern "C" void kernel_launch(void* const* d_in, const int* in_sizes, int n_in,
                              void* d_out, int out_size, void* d_ws, size_t ws_size,
                              hipStream_t stream)
{
    const float* enc      = (const float*)d_in[0];
    const float* h0       = (const float*)d_in[1];
    const float* c0       = (const float*)d_in[2];
    const int*   actions  = (const int*)  d_in[3];
    const float* emb_t    = (const float*)d_in[4];
    const float* Wih      = (const float*)d_in[5];
    const float* Whh      = (const float*)d_in[6];
    const float* bih      = (const float*)d_in[7];
    const float* bhh      = (const float*)d_in[8];
    const float* W_attn   = (const float*)d_in[9];
    const float* b_attn   = (const float*)d_in[10];
    const float* W_concat = (const float*)d_in[11];
    const float* b_concat = (const float*)d_in[12];
    const float* W_out    = (const float*)d_in[13];
    const float* W_critic = (const float*)d_in[14];
    const float* b_critic = (const float*)d_in[15];
    (void)in_sizes; (void)n_in; (void)out_size; (void)ws_size;

    const int M = BB * TT;                 // 32768

    float* out    = (float*)d_out;
    float* dact   = out;
    float* logits = out + M;
    float* values = out + M + (int64_t)M * OO;

    float* ws    = (float*)d_ws;
    float* gates = ws;
    float* xbuf  = ws + 33554432;
    float* cat   = ws + 41943040;
    float* keysR = ws + 58720256;
    float* keys  = keysR;
    uint4* Wpkh  = (uint4*)keysR;          // 1 MB; dead before keys
    float* scores = gates;
    float* qv     = gates;
    float* dec    = xbuf;

    const int64_t LWP = 32768;             // uint4s per layer in Wpkh
    const int64_t LW  = (int64_t)GATES * HT;

    // 1) embedding + decoder_action
    hipLaunchKernelGGL(embed_kernel, dim3(M), dim3(256), 0, stream,
                       actions, emb_t, xbuf, dact);
    // 2) repack Whh to fp16 register/LDS/stream layout
    hipLaunchKernelGGL(repack_whh_h_kernel, dim3(256), dim3(256), 0, stream,
                       Whh, Wpkh);
    // 3) layer-0 input GEMM (MFMA fp16): gates = emb @ Wih0^T + bih0 + bhh0
    hipLaunchKernelGGL((mfma_gemm_kernel<true, 0>), dim3(8, 256, 1), dim3(256), 0, stream,
                       xbuf, Wih, gates, HT, HT, HT, GATES,
                       (int64_t)0, (int64_t)0, (int64_t)0, bih, bhh);
    // 4) layer-0 recurrence -> X1 (xbuf, ldx=256)
    hipLaunchKernelGGL(lstm_rec_kernel, dim3(BB), dim3(512), 0, stream,
                       gates, Wpkh, h0, c0, xbuf, HT);
    // 5) layer-1 input GEMM (MFMA fp16)
    hipLaunchKernelGGL((mfma_gemm_kernel<true, 0>), dim3(8, 256, 1), dim3(256), 0, stream,
                       xbuf, Wih + LW, gates, HT, HT, HT, GATES,
                       (int64_t)0, (int64_t)0, (int64_t)0, bih + GATES, bhh + GATES);
    // 6) layer-1 recurrence -> cat[:, 0:256] (ldx=512)
    hipLaunchKernelGGL(lstm_rec_kernel, dim3(BB), dim3(512), 0, stream,
                       gates, Wpkh + LWP, h0 + BB * HT, c0 + BB * HT, cat, 2 * HT);
    // 7) keys = enc @ W_attn^T + b_attn (MFMA fp16; overwrites Wpkh region)
    hipLaunchKernelGGL((mfma_gemm_kernel<true, 0>), dim3(2, 256, 1), dim3(256), 0, stream,
                       enc, W_attn, keys, HT, HT, HT, HT,
                       (int64_t)0, (int64_t)0, (int64_t)0, b_attn, (const float*)nullptr);
    // 8) scores[b] = out[b] @ keys[b]^T  (fp32, precision-sensitive softmax input)
    hipLaunchKernelGGL((gemm128_kernel<true, 0>), dim3(4, 4, BB), dim3(256), 0, stream,
                       cat, keys, scores, HT, 2 * HT, HT, TT,
                       (int64_t)TT * 2 * HT, (int64_t)TT * HT, (int64_t)TT * TT,
                       (const float*)nullptr, (const float*)nullptr);
    // 9) softmax
    hipLaunchKernelGGL(softmax512_kernel, dim3(M / 4), dim3(256), 0, stream, scores);
    // 10) ctx[b] = P[b] @ enc[b] -> cat[:,256:]  (fp32)
    hipLaunchKernelGGL((gemm128_kernel<false, 0>), dim3(2, 4, BB), dim3(256), 0, stream,
                       scores, enc, cat + HT, TT, TT, HT, 2 * HT,
                       (int64_t)TT * TT, (int64_t)TT * HT, (int64_t)TT * 2 * HT,
                       (const float*)nullptr, (const float*)nullptr);
    // 11) dec = tanh(cat @ W_concat^T + b_concat) (MFMA fp16)
    hipLaunchKernelGGL((mfma_gemm_kernel<true, 1>), dim3(2, 256, 1), dim3(256), 0, stream,
                       cat, W_concat, dec, 2 * HT, 2 * HT, 2 * HT, HT,
                       (int64_t)0, (int64_t)0, (int64_t)0, b_concat, (const float*)nullptr);
    // 12) logits = dec @ W_out^T  (fp32 — output path)
    hipLaunchKernelGGL((gemm128_kernel<true, 0>), dim3(1, 256, 1), dim3(256), 0, stream,
                       dec, W_out, logits, HT, HT, HT, OO,
                       (int64_t)0, (int64_t)0, (int64_t)0,
                       (const float*)nullptr, (const float*)nullptr);
    // 13) qv = logits @ W_critic^T + b_critic  (fp32 — output path)
    hipLaunchKernelGGL((gemm128_kernel<true, 0>), dim3(1, 256, 1), dim3(256), 0, stream,
                       logits, W_critic, qv, OO, OO, OO, OO,
                       (int64_t)0, (int64_t)0, (int64_t)0, b_critic, (const float*)nullptr);
    // 14) values
    hipLaunchKernelGGL(values_kernel, dim3(M / 4), dim3(256), 0, stream,
                       qv, logits, values);
}